// Round 1
// baseline (12173.103 us; speedup 1.0000x reference)
//
#include <hip/hip_runtime.h>

#define NUM_USERS 100000
#define NUM_ITEMS 50000
#define NTOT (NUM_USERS + NUM_ITEMS)
#define EMBED_DIM 64
#define NNZ_E 4800000
#define NUM_LAYERS 3

// ---- init: cur = concat(user_emb, item_emb); out(acc) = cur ----
__global__ void k_init(const float* __restrict__ ue, const float* __restrict__ ie,
                       float* __restrict__ cur, float* __restrict__ out) {
    const long long total4 = (long long)NTOT * EMBED_DIM / 4;  // float4 count
    const long long u4 = (long long)NUM_USERS * EMBED_DIM / 4;
    const float4* ue4 = (const float4*)ue;
    const float4* ie4 = (const float4*)ie;
    float4* cur4 = (float4*)cur;
    float4* out4 = (float4*)out;
    for (long long i = (long long)blockIdx.x * blockDim.x + threadIdx.x;
         i < total4; i += (long long)gridDim.x * blockDim.x) {
        float4 v = (i < u4) ? ue4[i] : ie4[i - u4];
        cur4[i] = v;
        out4[i] = v;
    }
}

// ---- spmm: nxt[src] += val * cur[dst]  (16 lanes/edge, float4 gather) ----
__global__ void k_spmm(const int* __restrict__ src, const int* __restrict__ dst,
                       const float* __restrict__ val, const float* __restrict__ x,
                       float* __restrict__ nxt) {
    long long gid = (long long)blockIdx.x * blockDim.x + threadIdx.x;
    long long e = gid >> 4;
    if (e >= NNZ_E) return;
    int lane16 = (int)(gid & 15);
    int s = src[e];
    int d = dst[e];
    float v = val[e];
    const float4* xr = (const float4*)(x + (long long)d * EMBED_DIM);
    float4 m = xr[lane16];
    float* o = nxt + (long long)s * EMBED_DIM + lane16 * 4;
    atomicAdd(o + 0, v * m.x);
    atomicAdd(o + 1, v * m.y);
    atomicAdd(o + 2, v * m.z);
    atomicAdd(o + 3, v * m.w);
}

// ---- accum: out = (out + nxt) * scale ----
__global__ void k_accum(float* __restrict__ out, const float* __restrict__ nxt, float scale) {
    const long long total4 = (long long)NTOT * EMBED_DIM / 4;
    float4* out4 = (float4*)out;
    const float4* nxt4 = (const float4*)nxt;
    for (long long i = (long long)blockIdx.x * blockDim.x + threadIdx.x;
         i < total4; i += (long long)gridDim.x * blockDim.x) {
        float4 a = out4[i];
        float4 b = nxt4[i];
        a.x = (a.x + b.x) * scale;
        a.y = (a.y + b.y) * scale;
        a.z = (a.z + b.z) * scale;
        a.w = (a.w + b.w) * scale;
        out4[i] = a;
    }
}

extern "C" void kernel_launch(void* const* d_in, const int* in_sizes, int n_in,
                              void* d_out, int out_size, void* d_ws, size_t ws_size,
                              hipStream_t stream) {
    const float* user_emb = (const float*)d_in[0];
    const float* item_emb = (const float*)d_in[1];
    const int* edge_src   = (const int*)d_in[2];
    const int* edge_dst   = (const int*)d_in[3];
    const float* edge_val = (const float*)d_in[4];
    float* out = (float*)d_out;

    const size_t matBytes = (size_t)NTOT * EMBED_DIM * sizeof(float);
    float* bufA = (float*)d_ws;                       // cur
    float* bufB = (float*)((char*)d_ws + matBytes);   // nxt

    // init
    {
        dim3 blk(256), grd(2048);
        hipLaunchKernelGGL(k_init, grd, blk, 0, stream, user_emb, item_emb, bufA, out);
    }

    float* cur = bufA;
    float* nxt = bufB;
    const long long spmmThreads = (long long)NNZ_E * 16;
    const int spmmBlocks = (int)((spmmThreads + 255) / 256);

    for (int layer = 0; layer < NUM_LAYERS; ++layer) {
        hipMemsetAsync(nxt, 0, matBytes, stream);
        hipLaunchKernelGGL(k_spmm, dim3(spmmBlocks), dim3(256), 0, stream,
                           edge_src, edge_dst, edge_val, cur, nxt);
        float scale = (layer == NUM_LAYERS - 1) ? (1.0f / (NUM_LAYERS + 1)) : 1.0f;
        hipLaunchKernelGGL(k_accum, dim3(2048), dim3(256), 0, stream, out, nxt, scale);
        // swap
        float* t = cur; cur = nxt; nxt = t;
    }
}

// Round 2
// 1130.844 us; speedup vs baseline: 10.7646x; 10.7646x over previous
//
#include <hip/hip_runtime.h>

#define NUM_USERS 100000
#define NUM_ITEMS 50000
#define NTOT (NUM_USERS + NUM_ITEMS)
#define EMBED_DIM 64
#define NNZ_E 4800000
#define NUM_LAYERS 3

// ---------------- init: cur = concat(user_emb, item_emb); out(acc) = cur ----
__global__ void k_init(const float* __restrict__ ue, const float* __restrict__ ie,
                       float* __restrict__ cur, float* __restrict__ out) {
    const long long total4 = (long long)NTOT * EMBED_DIM / 4;
    const long long u4 = (long long)NUM_USERS * EMBED_DIM / 4;
    const float4* ue4 = (const float4*)ue;
    const float4* ie4 = (const float4*)ie;
    float4* cur4 = (float4*)cur;
    float4* out4 = (float4*)out;
    for (long long i = (long long)blockIdx.x * blockDim.x + threadIdx.x;
         i < total4; i += (long long)gridDim.x * blockDim.x) {
        float4 v = (i < u4) ? ue4[i] : ie4[i - u4];
        cur4[i] = v;
        out4[i] = v;
    }
}

// ---------------- histogram of src ----------------
__global__ void k_hist(const int* __restrict__ src, int* __restrict__ counts) {
    int i = blockIdx.x * blockDim.x + threadIdx.x;
    if (i < NNZ_E) atomicAdd(&counts[src[i]], 1);
}

// ---------------- block-level exclusive scan (1024 elems / block of 256) ----
__global__ void k_scan1(const int* __restrict__ in, int* __restrict__ excl,
                        int* __restrict__ blockSums, int n) {
    __shared__ int sdata[256];
    int b = blockIdx.x;
    int t = threadIdx.x;
    int base = b * 1024 + t * 4;
    int v0 = (base + 0 < n) ? in[base + 0] : 0;
    int v1 = (base + 1 < n) ? in[base + 1] : 0;
    int v2 = (base + 2 < n) ? in[base + 2] : 0;
    int v3 = (base + 3 < n) ? in[base + 3] : 0;
    int tsum = v0 + v1 + v2 + v3;
    sdata[t] = tsum;
    __syncthreads();
    for (int off = 1; off < 256; off <<= 1) {
        int x = (t >= off) ? sdata[t - off] : 0;
        __syncthreads();
        sdata[t] += x;
        __syncthreads();
    }
    int texcl = sdata[t] - tsum;  // exclusive prefix of this thread's chunk
    if (base + 0 < n) excl[base + 0] = texcl;
    if (base + 1 < n) excl[base + 1] = texcl + v0;
    if (base + 2 < n) excl[base + 2] = texcl + v0 + v1;
    if (base + 3 < n) excl[base + 3] = texcl + v0 + v1 + v2;
    if (t == 255 && blockSums != nullptr) blockSums[b] = sdata[255];
}

// ---------------- add block offsets; produce row_ptr and cursor ----------------
__global__ void k_scan3(int* __restrict__ row_ptr, const int* __restrict__ blockExcl,
                        int* __restrict__ cursor, int n) {
    int i = blockIdx.x * blockDim.x + threadIdx.x;
    if (i < n) {
        int v = row_ptr[i] + blockExcl[i >> 10];
        row_ptr[i] = v;
        cursor[i] = v;
    }
    if (i == n) row_ptr[n] = NNZ_E;
}

// ---------------- scatter edges into CSR order (packed dst,val) ----------------
__global__ void k_scatter(const int* __restrict__ src, const int* __restrict__ dst,
                          const float* __restrict__ val, int* __restrict__ cursor,
                          int2* __restrict__ sorted) {
    int i = blockIdx.x * blockDim.x + threadIdx.x;
    if (i >= NNZ_E) return;
    int s = src[i];
    int slot = atomicAdd(&cursor[s], 1);
    sorted[slot] = make_int2(dst[i], __float_as_int(val[i]));
}

// ---------------- CSR SpMM fused with accumulation ----------------
// one wave per row; lane = embedding column
__global__ void __launch_bounds__(256)
k_spmm_csr(const int2* __restrict__ edges, const int* __restrict__ row_ptr,
           const float* __restrict__ x, float* __restrict__ nxt,
           float* __restrict__ out, float scale) {
    int row = blockIdx.x * (blockDim.x >> 6) + (threadIdx.x >> 6);
    int lane = threadIdx.x & 63;
    if (row >= NTOT) return;
    int beg = row_ptr[row];
    int end = row_ptr[row + 1];
    float acc = 0.f;
    int j = beg;
    for (; j + 8 <= end; j += 8) {
        int2 e[8];
        float xv[8];
#pragma unroll
        for (int k = 0; k < 8; ++k) e[k] = edges[j + k];
#pragma unroll
        for (int k = 0; k < 8; ++k) xv[k] = x[(long long)e[k].x * EMBED_DIM + lane];
#pragma unroll
        for (int k = 0; k < 8; ++k) acc = fmaf(__int_as_float(e[k].y), xv[k], acc);
    }
    for (; j < end; ++j) {
        int2 e = edges[j];
        acc = fmaf(__int_as_float(e.y), x[(long long)e.x * EMBED_DIM + lane], acc);
    }
    long long o = (long long)row * EMBED_DIM + lane;
    nxt[o] = acc;
    out[o] = (out[o] + acc) * scale;
}

extern "C" void kernel_launch(void* const* d_in, const int* in_sizes, int n_in,
                              void* d_out, int out_size, void* d_ws, size_t ws_size,
                              hipStream_t stream) {
    const float* user_emb = (const float*)d_in[0];
    const float* item_emb = (const float*)d_in[1];
    const int* edge_src   = (const int*)d_in[2];
    const int* edge_dst   = (const int*)d_in[3];
    const float* edge_val = (const float*)d_in[4];
    float* out = (float*)d_out;

    // workspace layout (all 256-B aligned)
    char* p = (char*)d_ws;
    const size_t matBytes = (size_t)NTOT * EMBED_DIM * sizeof(float);   // 38.4 MB
    float* bufA   = (float*)p;                 p += matBytes;
    float* bufB   = (float*)p;                 p += matBytes;
    int2*  sorted = (int2*)p;                  p += (size_t)NNZ_E * sizeof(int2);
    int*   row_ptr = (int*)p;                  p += ((size_t)NTOT + 8) * sizeof(int);
    int*   cursor  = (int*)p;                  p += (size_t)NTOT * sizeof(int);
    int*   blockSums = (int*)p;                p += 1024 * sizeof(int);
    int*   blockExcl = (int*)p;                p += 1024 * sizeof(int);

    // 1. init cur + out accumulator
    hipLaunchKernelGGL(k_init, dim3(2048), dim3(256), 0, stream, user_emb, item_emb, bufA, out);

    // 2. histogram (counts live in `cursor`)
    hipMemsetAsync(cursor, 0, (size_t)NTOT * sizeof(int), stream);
    hipLaunchKernelGGL(k_hist, dim3((NNZ_E + 255) / 256), dim3(256), 0, stream, edge_src, cursor);

    // 3. exclusive scan -> row_ptr
    const int scanBlocks = (NTOT + 1023) / 1024;  // 147
    hipLaunchKernelGGL(k_scan1, dim3(scanBlocks), dim3(256), 0, stream, cursor, row_ptr, blockSums, NTOT);
    hipLaunchKernelGGL(k_scan1, dim3(1), dim3(256), 0, stream, blockSums, blockExcl, (int*)nullptr, scanBlocks);
    hipLaunchKernelGGL(k_scan3, dim3((NTOT + 256) / 256 + 1), dim3(256), 0, stream, row_ptr, blockExcl, cursor, NTOT);

    // 4. scatter edges into CSR order
    hipLaunchKernelGGL(k_scatter, dim3((NNZ_E + 255) / 256), dim3(256), 0, stream,
                       edge_src, edge_dst, edge_val, cursor, sorted);

    // 5. three gather-SpMM layers, fused with accumulation
    float* cur = bufA;
    float* nxt = bufB;
    const int rowsPerBlock = 256 / 64;
    const int spmmBlocks = (NTOT + rowsPerBlock - 1) / rowsPerBlock;
    for (int layer = 0; layer < NUM_LAYERS; ++layer) {
        float scale = (layer == NUM_LAYERS - 1) ? (1.0f / (NUM_LAYERS + 1)) : 1.0f;
        hipLaunchKernelGGL(k_spmm_csr, dim3(spmmBlocks), dim3(256), 0, stream,
                           sorted, row_ptr, cur, nxt, out, scale);
        float* t = cur; cur = nxt; nxt = t;
    }
}

// Round 3
// 722.632 us; speedup vs baseline: 16.8455x; 1.5649x over previous
//
#include <hip/hip_runtime.h>

#define NUM_USERS 100000
#define NUM_ITEMS 50000
#define NTOT (NUM_USERS + NUM_ITEMS)
#define EMBED_DIM 64
#define NNZ_E 4800000
#define NUM_LAYERS 3

#define ROWS_PER_BUCKET 256
#define NBUCK ((NTOT + ROWS_PER_BUCKET - 1) / ROWS_PER_BUCKET)   // 586
#define BCAP 8960                   // mean 8191 + 8.5 sigma (sigma ~ 90)
#define EDGES_PER_BLOCK 8192
#define DMASK 0x3FFFF               // 18 bits for dst (< 150000 < 2^18)

// ---------------- init: cur = concat(user_emb, item_emb); out(acc) = cur ----
__global__ void k_init(const float* __restrict__ ue, const float* __restrict__ ie,
                       float* __restrict__ cur, float* __restrict__ out) {
    const long long total4 = (long long)NTOT * EMBED_DIM / 4;
    const long long u4 = (long long)NUM_USERS * EMBED_DIM / 4;
    const float4* ue4 = (const float4*)ue;
    const float4* ie4 = (const float4*)ie;
    float4* cur4 = (float4*)cur;
    float4* out4 = (float4*)out;
    for (long long i = (long long)blockIdx.x * blockDim.x + threadIdx.x;
         i < total4; i += (long long)gridDim.x * blockDim.x) {
        float4 v = (i < u4) ? ue4[i] : ie4[i - u4];
        cur4[i] = v;
        out4[i] = v;
    }
}

// ---------------- phase 1: coarse bucket scatter (block-aggregated) ----------
__global__ void __launch_bounds__(256)
k_bucket(const int* __restrict__ src, const int* __restrict__ dst,
         const float* __restrict__ val, int* __restrict__ cursor,
         int2* __restrict__ outA) {
    __shared__ int h[NBUCK];     // per-block bucket counts, then local cursors
    __shared__ int base[NBUCK];  // reserved global base per bucket
    for (int i = threadIdx.x; i < NBUCK; i += 256) h[i] = 0;
    __syncthreads();
    long long e0 = (long long)blockIdx.x * EDGES_PER_BLOCK;
    int n = (int)(((long long)NNZ_E - e0) < EDGES_PER_BLOCK ? (NNZ_E - e0)
                                                            : EDGES_PER_BLOCK);
    // count
    for (int i = threadIdx.x; i < n; i += 256)
        atomicAdd(&h[src[e0 + i] >> 8], 1);
    __syncthreads();
    // reserve
    for (int i = threadIdx.x; i < NBUCK; i += 256) {
        int c = h[i];
        base[i] = (c > 0) ? atomicAdd(&cursor[i], c) : 0;
        h[i] = 0;   // reuse as local cursor
    }
    __syncthreads();
    // scatter (packed: dst | row-in-bucket<<18, val)
    for (int i = threadIdx.x; i < n; i += 256) {
        int s = src[e0 + i];
        int d = dst[e0 + i];
        float v = val[e0 + i];
        int b = s >> 8;
        int off = base[b] + atomicAdd(&h[b], 1);
        outA[(long long)b * BCAP + off] =
            make_int2(d | ((s & 255) << 18), __float_as_int(v));
    }
}

// ---------------- phase 2: per-bucket LDS counting sort -> row-grouped ------
__global__ void __launch_bounds__(256)
k_sortbucket(const int2* __restrict__ inAll, const int* __restrict__ cursor,
             int2* __restrict__ outB, int* __restrict__ rp_beg,
             int* __restrict__ rp_end) {
    __shared__ int h[ROWS_PER_BUCKET];
    __shared__ int excl[ROWS_PER_BUCKET];
    __shared__ int cur[ROWS_PER_BUCKET];
    int b = blockIdx.x;
    int t = threadIdx.x;
    int cnt = cursor[b];
    const int2* in = inAll + (long long)b * BCAP;
    h[t] = 0;
    __syncthreads();
    for (int i = t; i < cnt; i += 256)
        atomicAdd(&h[(in[i].x >> 18) & 255], 1);
    __syncthreads();
    int v = h[t];
    excl[t] = v;
    __syncthreads();
    for (int off = 1; off < 256; off <<= 1) {
        int x = (t >= off) ? excl[t - off] : 0;
        __syncthreads();
        excl[t] += x;
        __syncthreads();
    }
    int myExcl = excl[t] - v;    // exclusive prefix
    cur[t] = myExcl;
    long long gb = (long long)b * BCAP;
    int row = b * ROWS_PER_BUCKET + t;
    if (row < NTOT) {
        rp_beg[row] = (int)(gb + myExcl);
        rp_end[row] = (int)(gb + myExcl + v);
    }
    __syncthreads();
    for (int i = t; i < cnt; i += 256) {
        int2 e = in[i];
        int r = (e.x >> 18) & 255;
        int slot = atomicAdd(&cur[r], 1);
        outB[gb + slot] = e;
    }
}

// ---------------- CSR SpMM fused with accumulation ----------------
// one wave per row; lane = embedding column
__global__ void __launch_bounds__(256)
k_spmm_csr(const int2* __restrict__ edges, const int* __restrict__ rp_beg,
           const int* __restrict__ rp_end, const float* __restrict__ x,
           float* __restrict__ nxt, float* __restrict__ out, float scale) {
    int row = blockIdx.x * (blockDim.x >> 6) + (threadIdx.x >> 6);
    int lane = threadIdx.x & 63;
    if (row >= NTOT) return;
    int beg = rp_beg[row];
    int end = rp_end[row];
    float acc = 0.f;
    int j = beg;
    for (; j + 8 <= end; j += 8) {
        int2 e[8];
        float xv[8];
#pragma unroll
        for (int k = 0; k < 8; ++k) e[k] = edges[j + k];
#pragma unroll
        for (int k = 0; k < 8; ++k)
            xv[k] = x[(long long)(e[k].x & DMASK) * EMBED_DIM + lane];
#pragma unroll
        for (int k = 0; k < 8; ++k) acc = fmaf(__int_as_float(e[k].y), xv[k], acc);
    }
    for (; j < end; ++j) {
        int2 e = edges[j];
        acc = fmaf(__int_as_float(e.y),
                   x[(long long)(e.x & DMASK) * EMBED_DIM + lane], acc);
    }
    long long o = (long long)row * EMBED_DIM + lane;
    nxt[o] = acc;
    out[o] = (out[o] + acc) * scale;
}

extern "C" void kernel_launch(void* const* d_in, const int* in_sizes, int n_in,
                              void* d_out, int out_size, void* d_ws, size_t ws_size,
                              hipStream_t stream) {
    const float* user_emb = (const float*)d_in[0];
    const float* item_emb = (const float*)d_in[1];
    const int* edge_src   = (const int*)d_in[2];
    const int* edge_dst   = (const int*)d_in[3];
    const float* edge_val = (const float*)d_in[4];
    float* out = (float*)d_out;

    // ---- workspace layout ----
    // [0 .. 76.8MB)      : bufA (38.4MB) + bufB (38.4MB)
    //                      bucketedA (42MB) ALIASES this region (dead before k_init)
    // [76.8 .. 118.8MB)  : bucketedB (final row-grouped edges, live all layers)
    // then rp_beg, rp_end, cursor
    char* p = (char*)d_ws;
    const size_t matBytes = (size_t)NTOT * EMBED_DIM * sizeof(float);     // 38.4 MB
    const size_t buckBytes = (size_t)NBUCK * BCAP * sizeof(int2);         // 42.0 MB
    float* bufA = (float*)p;
    float* bufB = (float*)(p + matBytes);
    int2*  bucketedA = (int2*)p;                  // alias of bufA/bufB region
    p += 2 * matBytes;
    int2*  bucketedB = (int2*)p;                  p += buckBytes;
    int*   rp_beg = (int*)p;                      p += ((size_t)NTOT + 8) * sizeof(int);
    int*   rp_end = (int*)p;                      p += ((size_t)NTOT + 8) * sizeof(int);
    int*   cursor = (int*)p;                      p += (size_t)NBUCK * sizeof(int);

    // 1. coarse bucket scatter
    hipMemsetAsync(cursor, 0, (size_t)NBUCK * sizeof(int), stream);
    const int bucketBlocks = (NNZ_E + EDGES_PER_BLOCK - 1) / EDGES_PER_BLOCK;  // 586
    hipLaunchKernelGGL(k_bucket, dim3(bucketBlocks), dim3(256), 0, stream,
                       edge_src, edge_dst, edge_val, cursor, bucketedA);

    // 2. per-bucket counting sort -> bucketedB + row ptrs
    hipLaunchKernelGGL(k_sortbucket, dim3(NBUCK), dim3(256), 0, stream,
                       bucketedA, cursor, bucketedB, rp_beg, rp_end);

    // 3. init cur + out accumulator (overwrites bucketedA region)
    hipLaunchKernelGGL(k_init, dim3(2048), dim3(256), 0, stream,
                       user_emb, item_emb, bufA, out);

    // 4. three gather-SpMM layers, fused with accumulation
    float* cur = bufA;
    float* nxt = bufB;
    const int rowsPerBlock = 256 / 64;
    const int spmmBlocks = (NTOT + rowsPerBlock - 1) / rowsPerBlock;
    for (int layer = 0; layer < NUM_LAYERS; ++layer) {
        float scale = (layer == NUM_LAYERS - 1) ? (1.0f / (NUM_LAYERS + 1)) : 1.0f;
        hipLaunchKernelGGL(k_spmm_csr, dim3(spmmBlocks), dim3(256), 0, stream,
                           bucketedB, rp_beg, rp_end, cur, nxt, out, scale);
        float* t = cur; cur = nxt; nxt = t;
    }
}